// Round 1
// baseline (480.245 us; speedup 1.0000x reference)
//
#include <hip/hip_runtime.h>
#include <cstdint>

#define NEG (-1e12f)
constexpr int Bn = 32, Ln = 256, Tn = 2048;
constexpr int TB = Tn / 64;            // 32 uint64 words of t-bits per text row

// ---------------- zero the whole output buffer ----------------
__global__ void k_zero(float* __restrict__ out, int n4, int total) {
    int idx = blockIdx.x * blockDim.x + threadIdx.x;
    int stride = gridDim.x * blockDim.x;
    float4 z = make_float4(0.f, 0.f, 0.f, 0.f);
    for (int i = idx; i < n4; i += stride) reinterpret_cast<float4*>(out)[i] = z;
    if (idx == 0) {
        for (int i = n4 * 4; i < total; ++i) out[i] = 0.f;
    }
}

// ---------------- guided attention loss: per-block partial sums ----------------
__global__ void k_loss_partial(const float* __restrict__ att,
                               const int* __restrict__ ilen,
                               const int* __restrict__ olen,
                               float* __restrict__ partial) {
    const int N4 = Bn * Tn * Ln / 4;
    int tid = threadIdx.x;
    int idx = blockIdx.x * blockDim.x + tid;
    int stride = gridDim.x * blockDim.x;
    float acc = 0.f;
    for (int v = idx; v < N4; v += stride) {
        int flat = v << 2;                       // att is (B, T, L), L=256 T=2048
        int b  = flat >> 19;                     // / (T*L)
        int t  = (flat >> 8) & (Tn - 1);
        int l0 = flat & (Ln - 1);
        int ili = ilen[b];
        int oli = olen[b];
        if (t >= oli) continue;
        float il = (float)ili, ol = (float)oli;
        float tf = (float)t / ol;
        float4 a = reinterpret_cast<const float4*>(att)[v];
        #pragma unroll
        for (int c = 0; c < 4; ++c) {
            int l = l0 + c;
            float av = (c == 0) ? a.x : (c == 1) ? a.y : (c == 2) ? a.z : a.w;
            if (l < ili) {
                float d = (float)l / il - tf;
                acc += (1.f - __expf(-d * d * 3.125f)) * av;   // 1/(2*0.4^2)=3.125
            }
        }
    }
    for (int off = 32; off > 0; off >>= 1) acc += __shfl_down(acc, off, 64);
    __shared__ float sw[4];
    if ((tid & 63) == 0) sw[tid >> 6] = acc;
    __syncthreads();
    if (tid == 0) partial[blockIdx.x] = (sw[0] + sw[1]) + (sw[2] + sw[3]);
}

// ---------------- deterministic final loss reduce ----------------
__global__ void k_loss_final(const float* __restrict__ partial, int np,
                             const int* __restrict__ olen,
                             float* __restrict__ out) {
    int tid = threadIdx.x;
    float acc = 0.f;
    for (int i = tid; i < np; i += 256) acc += partial[i];
    for (int off = 32; off > 0; off >>= 1) acc += __shfl_down(acc, off, 64);
    __shared__ float sw[4];
    if ((tid & 63) == 0) sw[tid >> 6] = acc;
    __syncthreads();
    if (tid == 0) {
        float tot = (sw[0] + sw[1]) + (sw[2] + sw[3]);
        int so = 0;
        for (int i = 0; i < Bn; ++i) so += olen[i];
        out[0] = tot / (float)so;
    }
}

// ---------------- Viterbi forward: one batch per wave, 4 rows per lane ----------------
// Stores decision bits transposed: bits[b][l][t>>6], bit (t&63), where
// bit(t,l) = beta[t][(l-1)%256] > beta[t][l]   (torch wrap semantics)
__global__ void __launch_bounds__(64) k_forward(const float* __restrict__ logp,
                                                uint64_t* __restrict__ bits) {
    int b = blockIdx.x;
    int lane = threadIdx.x;
    const float* lp  = logp + (size_t)b * (Ln * Tn);
    const float* p0r = lp + (size_t)(4 * lane + 0) * Tn;
    const float* p1r = lp + (size_t)(4 * lane + 1) * Tn;
    const float* p2r = lp + (size_t)(4 * lane + 2) * Tn;
    const float* p3r = lp + (size_t)(4 * lane + 3) * Tn;
    uint64_t* bb = bits + (size_t)b * (Ln * TB);
    int src = (lane + 63) & 63;                 // lane-1 mod 64 (wraps 0 -> 63)
    float pv0 = NEG, pv1 = NEG, pv2 = NEG, pv3 = NEG;
    float left = NEG;                           // beta[t-1][4*lane-1], NEG for lane 0
    uint32_t a0lo = 0, a0hi = 0, a1lo = 0, a1hi = 0;
    uint32_t a2lo = 0, a2hi = 0, a3lo = 0, a3hi = 0;
    for (int tb4 = 0; tb4 < Tn / 4; ++tb4) {
        float4 q0 = *reinterpret_cast<const float4*>(p0r + 4 * tb4);
        float4 q1 = *reinterpret_cast<const float4*>(p1r + 4 * tb4);
        float4 q2 = *reinterpret_cast<const float4*>(p2r + 4 * tb4);
        float4 q3 = *reinterpret_cast<const float4*>(p3r + 4 * tb4);
        #pragma unroll
        for (int j = 0; j < 4; ++j) {
            int t = 4 * tb4 + j;
            float l0v = (j == 0) ? q0.x : (j == 1) ? q0.y : (j == 2) ? q0.z : q0.w;
            float l1v = (j == 0) ? q1.x : (j == 1) ? q1.y : (j == 2) ? q1.z : q1.w;
            float l2v = (j == 0) ? q2.x : (j == 1) ? q2.y : (j == 2) ? q2.z : q2.w;
            float l3v = (j == 0) ? q3.x : (j == 1) ? q3.y : (j == 2) ? q3.z : q3.w;
            float c0, c1, c2, c3;
            if (t == 0) {
                // init: all NEG except global row 0 = logp[b,0,0]
                c0 = (lane == 0) ? l0v : NEG;
                c1 = NEG; c2 = NEG; c3 = NEG;
            } else {
                c0 = fmaxf(pv0, left) + l0v;
                c1 = fmaxf(pv1, pv0) + l1v;
                c2 = fmaxf(pv2, pv1) + l2v;
                c3 = fmaxf(pv3, pv2) + l3v;
            }
            float s = __shfl(c3, src, 64);      // beta[t][4*lane-1] (lane0: row 255)
            // strict-greater via sign of subtraction (exact: a>b <=> signbit(b-a))
            uint32_t b0 = __float_as_uint(c0 - s)  >> 31;
            uint32_t b1 = __float_as_uint(c1 - c0) >> 31;
            uint32_t b2 = __float_as_uint(c2 - c1) >> 31;
            uint32_t b3 = __float_as_uint(c3 - c2) >> 31;
            int sh = t & 31;
            if (((t >> 5) & 1) == 0) {
                a0lo |= b0 << sh; a1lo |= b1 << sh; a2lo |= b2 << sh; a3lo |= b3 << sh;
            } else {
                a0hi |= b0 << sh; a1hi |= b1 << sh; a2hi |= b2 << sh; a3hi |= b3 << sh;
            }
            if ((t & 63) == 63) {
                int w = t >> 6;
                bb[(size_t)(4 * lane + 0) * TB + w] = ((uint64_t)a0hi << 32) | a0lo;
                bb[(size_t)(4 * lane + 1) * TB + w] = ((uint64_t)a1hi << 32) | a1lo;
                bb[(size_t)(4 * lane + 2) * TB + w] = ((uint64_t)a2hi << 32) | a2lo;
                bb[(size_t)(4 * lane + 3) * TB + w] = ((uint64_t)a3hi << 32) | a3lo;
                a0lo = a0hi = a1lo = a1hi = a2lo = a2hi = a3lo = a3hi = 0;
            }
            left = (lane == 0) ? NEG : s;
            pv0 = c0; pv1 = c1; pv2 = c2; pv3 = c3;
        }
    }
}

// ---------------- backtrack + scatter ones (run-length over t-bit words) ----------------
__global__ void k_backtrack(const uint64_t* __restrict__ bits,
                            const int* __restrict__ ilen,
                            const int* __restrict__ olen,
                            float* __restrict__ out) {
    if (threadIdx.x != 0) return;
    int b = blockIdx.x;
    int tl = ilen[b], ml = olen[b];
    const uint64_t* bb = bits + (size_t)b * (Ln * TB);
    float* ob = out + 1 + (size_t)b * (Ln * Tn);   // align[b] as (L, T), after loss scalar
    int r = tl - 1;
    ob[(size_t)r * Tn + (ml - 1)] = 1.0f;          // t_out = ml-1 holds rows0
    int p = ml - 2;                                 // current column cm1 (== t_out)
    const uint64_t* rowp = bb + (size_t)r * TB;
    float* orow = ob + (size_t)r * Tn;
    while (p >= 0) {
        uint64_t w = rowp[p >> 6];
        int pb = p & 63;
        uint64_t mask = (pb == 63) ? ~0ull : ((1ull << (pb + 1)) - 1ull);
        uint64_t m = w & mask;
        int base = p & ~63;
        if (m == 0) {
            // stay at row r for all columns [base, p]
            for (int t = base; t <= p; ++t) orow[t] = 1.0f;
            p = base - 1;
        } else {
            int q = 63 - __builtin_clzll(m);       // highest set bit <= p
            int tq = base + q;
            for (int t = tq + 1; t <= p; ++t) orow[t] = 1.0f;
            r -= 1;                                 // advance (go) at column tq
            if (r < 0) break;                       // saturates at -1: all-zero columns
            rowp -= TB;
            orow -= Tn;
            orow[tq] = 1.0f;
            p = tq - 1;
        }
    }
}

extern "C" void kernel_launch(void* const* d_in, const int* in_sizes, int n_in,
                              void* d_out, int out_size, void* d_ws, size_t ws_size,
                              hipStream_t stream) {
    const float* logp = (const float*)d_in[0];
    const float* att  = (const float*)d_in[1];
    const int* tlen   = (const int*)d_in[2];
    const int* mlen   = (const int*)d_in[3];
    float* out = (float*)d_out;
    uint64_t* bits = (uint64_t*)d_ws;                                  // 2 MB
    float* partial = (float*)((char*)d_ws + (size_t)Bn * Ln * TB * 8); // +4 KB
    int n4 = out_size >> 2;
    k_zero<<<1024, 256, 0, stream>>>(out, n4, out_size);
    k_loss_partial<<<1024, 256, 0, stream>>>(att, tlen, mlen, partial);
    k_loss_final<<<1, 256, 0, stream>>>(partial, 1024, mlen, out);
    k_forward<<<Bn, 64, 0, stream>>>(logp, bits);
    k_backtrack<<<Bn, 64, 0, stream>>>(bits, tlen, mlen, out);
}

// Round 2
// 351.998 us; speedup vs baseline: 1.3643x; 1.3643x over previous
//
#include <hip/hip_runtime.h>
#include <cstdint>

#define NEG (-1e12f)
constexpr int Bn = 32, Ln = 256, Tn = 2048;
constexpr int TB = Tn / 64;                 // 32 uint64 words of t-bits per text row
constexpr int WST_BSTRIDE = (Tn - 1) * Ln;  // 524032 floats per batch in wsT (t>=1 only)

// ---------------- fused transpose + loss partials ----------------
// blocks [0,4096):  transpose logp[b][l][t] -> wsT[b][t-1][l] for t>=1
//                   wsT lives in d_out (scratch; k_zero erases it later)
// blocks [4096,5120): guided-attention loss per-block partial sums
__global__ void k_trans_loss(const float* __restrict__ logp,
                             const float* __restrict__ att,
                             const int* __restrict__ ilen,
                             const int* __restrict__ olen,
                             float* __restrict__ wsT,
                             float* __restrict__ partial) {
    __shared__ float tile[64 * 68];
    int bid = blockIdx.x;
    int tid = threadIdx.x;
    if (bid < 4096) {
        int b = bid >> 7, rest = bid & 127;
        int lt = rest >> 5, tt = rest & 31;      // 4 l-tiles x 32 t-tiles of 64x64
        const float* src = logp + ((size_t)b * Ln + lt * 64) * Tn + (size_t)tt * 64;
        int lr = tid >> 4, tc4 = (tid & 15) * 4;
        #pragma unroll
        for (int pass = 0; pass < 4; ++pass) {
            int l_loc = pass * 16 + lr;
            float4 v = *(const float4*)(src + (size_t)l_loc * Tn + tc4);
            *(float4*)(&tile[l_loc * 68 + tc4]) = v;
        }
        __syncthreads();
        float* dst = wsT + (size_t)b * WST_BSTRIDE + lt * 64;
        #pragma unroll
        for (int pass = 0; pass < 4; ++pass) {
            int t_loc = pass * 16 + lr;
            float4 v;
            v.x = tile[(tc4 + 0) * 68 + t_loc];
            v.y = tile[(tc4 + 1) * 68 + t_loc];
            v.z = tile[(tc4 + 2) * 68 + t_loc];
            v.w = tile[(tc4 + 3) * 68 + t_loc];
            int tg = tt * 64 + t_loc;
            if (tg >= 1) *(float4*)(dst + (size_t)(tg - 1) * Ln + tc4) = v;
        }
    } else {
        const int N4 = Bn * Tn * Ln / 4;
        int idx = (bid - 4096) * blockDim.x + tid;
        int stride = 1024 * 256;
        float acc = 0.f;
        for (int v = idx; v < N4; v += stride) {
            int flat = v << 2;                   // att is (B, T, L)
            int b  = flat >> 19;
            int t  = (flat >> 8) & (Tn - 1);
            int l0 = flat & (Ln - 1);
            int ili = ilen[b];
            int oli = olen[b];
            if (t >= oli) continue;
            float il = (float)ili, ol = (float)oli;
            float tf = (float)t / ol;
            float4 a = reinterpret_cast<const float4*>(att)[v];
            #pragma unroll
            for (int c = 0; c < 4; ++c) {
                int l = l0 + c;
                float av = (c == 0) ? a.x : (c == 1) ? a.y : (c == 2) ? a.z : a.w;
                if (l < ili) {
                    float d = (float)l / il - tf;
                    acc += (1.f - __expf(-d * d * 3.125f)) * av;
                }
            }
        }
        for (int off = 32; off > 0; off >>= 1) acc += __shfl_down(acc, off, 64);
        __shared__ float sw[4];
        if ((tid & 63) == 0) sw[tid >> 6] = acc;
        __syncthreads();
        if (tid == 0) partial[bid - 4096] = (sw[0] + sw[1]) + (sw[2] + sw[3]);
    }
}

// ---------------- deterministic final loss reduce ----------------
__global__ void k_loss_final(const float* __restrict__ partial, int np,
                             const int* __restrict__ olen,
                             float* __restrict__ out) {
    int tid = threadIdx.x;
    float acc = 0.f;
    for (int i = tid; i < np; i += 256) acc += partial[i];
    for (int off = 32; off > 0; off >>= 1) acc += __shfl_down(acc, off, 64);
    __shared__ float sw[4];
    if ((tid & 63) == 0) sw[tid >> 6] = acc;
    __syncthreads();
    if (tid == 0) {
        float tot = (sw[0] + sw[1]) + (sw[2] + sw[3]);
        int so = 0;
        for (int i = 0; i < Bn; ++i) so += olen[i];
        out[0] = tot / (float)so;
    }
}

// ---------------- zero the whole output buffer ----------------
__global__ void k_zero(float* __restrict__ out, int n4, int total) {
    int idx = blockIdx.x * blockDim.x + threadIdx.x;
    int stride = gridDim.x * blockDim.x;
    float4 z = make_float4(0.f, 0.f, 0.f, 0.f);
    for (int i = idx; i < n4; i += stride) reinterpret_cast<float4*>(out)[i] = z;
    if (idx == 0) {
        for (int i = n4 * 4; i < total; ++i) out[i] = 0.f;
    }
}

// ---------------- Viterbi forward: coalesced transposed reads + reg prefetch ----------------
// bit(t,l) = beta[t][(l-1)%256] > beta[t][l]  (torch wrap), packed bits[b][l][t>>6]
#define STEP(T, Q) { \
    float n0 = fmaxf(pv0, left) + (Q).x; \
    float n1 = fmaxf(pv1, pv0) + (Q).y; \
    float n2 = fmaxf(pv2, pv1) + (Q).z; \
    float n3 = fmaxf(pv3, pv2) + (Q).w; \
    float sv = __shfl(n3, src, 64); \
    uint32_t e0 = __float_as_uint(n0 - sv) >> 31; \
    uint32_t e1 = __float_as_uint(n1 - n0) >> 31; \
    uint32_t e2 = __float_as_uint(n2 - n1) >> 31; \
    uint32_t e3 = __float_as_uint(n3 - n2) >> 31; \
    int sh = (T) & 31; \
    if ((((T) >> 5) & 1) == 0) { a0lo |= e0 << sh; a1lo |= e1 << sh; a2lo |= e2 << sh; a3lo |= e3 << sh; } \
    else                       { a0hi |= e0 << sh; a1hi |= e1 << sh; a2hi |= e2 << sh; a3hi |= e3 << sh; } \
    if (((T) & 63) == 63) { \
        int w = (T) >> 6; \
        bb[(size_t)(4 * lane + 0) * TB + w] = ((uint64_t)a0hi << 32) | a0lo; \
        bb[(size_t)(4 * lane + 1) * TB + w] = ((uint64_t)a1hi << 32) | a1lo; \
        bb[(size_t)(4 * lane + 2) * TB + w] = ((uint64_t)a2hi << 32) | a2lo; \
        bb[(size_t)(4 * lane + 3) * TB + w] = ((uint64_t)a3hi << 32) | a3lo; \
        a0lo = a0hi = a1lo = a1hi = a2lo = a2hi = a3lo = a3hi = 0; \
    } \
    left = (lane == 0) ? NEG : sv; \
    pv0 = n0; pv1 = n1; pv2 = n2; pv3 = n3; }

#define LOADX(BUF, C) { \
    _Pragma("unroll") \
    for (int j = 0; j < 16; ++j) (BUF)[j] = wb[((C) * 16 + j) * 64]; }

#define COMPUTE(BUF, C) { \
    _Pragma("unroll") \
    for (int j = 0; j < 16; ++j) STEP(1 + (C) * 16 + j, (BUF)[j]); }

__global__ void __launch_bounds__(64, 1) k_forward2(const float* __restrict__ logp,
                                                    const float* __restrict__ wsT,
                                                    uint64_t* __restrict__ bits) {
    int b = blockIdx.x;
    int lane = threadIdx.x;
    int src = (lane + 63) & 63;
    uint64_t* bb = bits + (size_t)b * (Ln * TB);
    const float4* wb = (const float4*)(wsT + (size_t)b * WST_BSTRIDE) + lane;

    float pv0, pv1, pv2, pv3, left;
    uint32_t a0lo = 0, a0hi = 0, a1lo = 0, a1hi = 0;
    uint32_t a2lo = 0, a2hi = 0, a3lo = 0, a3hi = 0;

    // ---- peeled t = 0 (exact init: row0 = logp[b,0,0], others = NEG) ----
    {
        float lp00 = logp[(size_t)b * (Ln * Tn)];
        float n0 = (lane == 0) ? lp00 : NEG;
        float n1 = NEG, n2 = NEG, n3 = NEG;
        float sv = __shfl(n3, src, 64);
        uint32_t e0 = __float_as_uint(n0 - sv) >> 31;
        uint32_t e1 = __float_as_uint(n1 - n0) >> 31;
        uint32_t e2 = __float_as_uint(n2 - n1) >> 31;
        uint32_t e3 = __float_as_uint(n3 - n2) >> 31;
        a0lo |= e0; a1lo |= e1; a2lo |= e2; a3lo |= e3;   // sh = 0
        left = NEG;
        pv0 = n0; pv1 = n1; pv2 = n2; pv3 = n3;
    }

    // ---- t = 1..2047 in 128 chunks of 16, double-buffered register prefetch ----
    // (chunk 127 step j=15 is t=2048: reads in-bounds garbage, writes nothing)
    float4 bufA[16], bufB[16];
    LOADX(bufA, 0);
    for (int c = 0; c < 126; c += 2) {
        LOADX(bufB, c + 1);
        COMPUTE(bufA, c);
        LOADX(bufA, c + 2);
        COMPUTE(bufB, c + 1);
    }
    LOADX(bufB, 127);
    COMPUTE(bufA, 126);
    COMPUTE(bufB, 127);
}

// ---------------- backtrack from LDS-resident bits + scatter ones ----------------
__global__ void __launch_bounds__(64) k_backtrack2(const uint64_t* __restrict__ bits,
                                                   const int* __restrict__ ilen,
                                                   const int* __restrict__ olen,
                                                   float* __restrict__ out) {
    __shared__ uint64_t sb[Ln * TB];   // 64 KB: this batch's full bit array
    int b = blockIdx.x, lane = threadIdx.x;
    const ulonglong2* g = (const ulonglong2*)(bits + (size_t)b * (Ln * TB));
    ulonglong2* s2 = (ulonglong2*)sb;
    #pragma unroll
    for (int i = 0; i < 64; ++i) s2[i * 64 + lane] = g[i * 64 + lane];
    __syncthreads();
    if (lane != 0) return;

    int tl = ilen[b], ml = olen[b];
    float* ob = out + 1 + (size_t)b * (Ln * Tn);   // align[b] as (L, T)
    int r = tl - 1;
    ob[(size_t)r * Tn + (ml - 1)] = 1.0f;
    int p = ml - 2;
    const uint64_t* rowp = sb + (size_t)r * TB;
    float* orow = ob + (size_t)r * Tn;
    while (p >= 0) {
        uint64_t w = rowp[p >> 6];
        int pb = p & 63;
        uint64_t mask = (pb == 63) ? ~0ull : ((1ull << (pb + 1)) - 1ull);
        uint64_t m = w & mask;
        int base = p & ~63;
        if (m == 0) {
            for (int t = base; t <= p; ++t) orow[t] = 1.0f;
            p = base - 1;
        } else {
            int q = 63 - __builtin_clzll(m);
            int tq = base + q;
            for (int t = tq + 1; t <= p; ++t) orow[t] = 1.0f;
            r -= 1;
            if (r < 0) break;
            rowp -= TB;
            orow -= Tn;
            orow[tq] = 1.0f;
            p = tq - 1;
        }
    }
}

extern "C" void kernel_launch(void* const* d_in, const int* in_sizes, int n_in,
                              void* d_out, int out_size, void* d_ws, size_t ws_size,
                              hipStream_t stream) {
    const float* logp = (const float*)d_in[0];
    const float* att  = (const float*)d_in[1];
    const int* tlen   = (const int*)d_in[2];
    const int* mlen   = (const int*)d_in[3];
    float* out = (float*)d_out;
    uint64_t* bits = (uint64_t*)d_ws;                                  // 2 MB
    float* partial = (float*)((char*)d_ws + (size_t)Bn * Ln * TB * 8); // +4 KB
    int n4 = out_size >> 2;

    // 1) transpose logp into d_out-scratch + loss partials (fused, full GPU)
    k_trans_loss<<<5120, 256, 0, stream>>>(logp, att, tlen, mlen, out, partial);
    // 2) forward DP: coalesced reads of the transpose, bits -> ws
    k_forward2<<<Bn, 64, 0, stream>>>(logp, out, bits);
    // 3) zero output (erases the transpose scratch)
    k_zero<<<2048, 256, 0, stream>>>(out, n4, out_size);
    // 4) backtrack (bits staged to LDS) + scatter ones
    k_backtrack2<<<Bn, 64, 0, stream>>>(bits, tlen, mlen, out);
    // 5) final loss reduce -> out[0]
    k_loss_final<<<1, 256, 0, stream>>>(partial, 1024, mlen, out);
}

// Round 3
// 297.549 us; speedup vs baseline: 1.6140x; 1.1830x over previous
//
#include <hip/hip_runtime.h>
#include <cstdint>

#define NEG (-1e12f)
constexpr int Bn = 32, Ln = 256, Tn = 2048;
constexpr int TB = Tn / 64;                 // 32 uint64 words of t-bits per text row
constexpr int WST_BSTRIDE = (Tn - 1) * Ln;  // 524032 floats per batch in wsT (t>=1 only)

// ---------------- fused transpose + loss partials ----------------
// blocks [0,4096):  transpose logp[b][l][t] -> wsT[b][t-1][l] for t>=1 (wsT = d_out scratch)
// blocks [4096,5120): guided-attention loss per-block partial sums
__global__ void k_trans_loss(const float* __restrict__ logp,
                             const float* __restrict__ att,
                             const int* __restrict__ ilen,
                             const int* __restrict__ olen,
                             float* __restrict__ wsT,
                             float* __restrict__ partial) {
    __shared__ float tile[64 * 68];
    int bid = blockIdx.x;
    int tid = threadIdx.x;
    if (bid < 4096) {
        int b = bid >> 7, rest = bid & 127;
        int lt = rest >> 5, tt = rest & 31;      // 4 l-tiles x 32 t-tiles of 64x64
        const float* src = logp + ((size_t)b * Ln + lt * 64) * Tn + (size_t)tt * 64;
        int lr = tid >> 4, tc4 = (tid & 15) * 4;
        #pragma unroll
        for (int pass = 0; pass < 4; ++pass) {
            int l_loc = pass * 16 + lr;
            float4 v = *(const float4*)(src + (size_t)l_loc * Tn + tc4);
            *(float4*)(&tile[l_loc * 68 + tc4]) = v;
        }
        __syncthreads();
        float* dst = wsT + (size_t)b * WST_BSTRIDE + lt * 64;
        #pragma unroll
        for (int pass = 0; pass < 4; ++pass) {
            int t_loc = pass * 16 + lr;
            float4 v;
            v.x = tile[(tc4 + 0) * 68 + t_loc];
            v.y = tile[(tc4 + 1) * 68 + t_loc];
            v.z = tile[(tc4 + 2) * 68 + t_loc];
            v.w = tile[(tc4 + 3) * 68 + t_loc];
            int tg = tt * 64 + t_loc;
            if (tg >= 1) *(float4*)(dst + (size_t)(tg - 1) * Ln + tc4) = v;
        }
    } else {
        const int N4 = Bn * Tn * Ln / 4;
        int idx = (bid - 4096) * blockDim.x + tid;
        int stride = 1024 * 256;
        float acc = 0.f;
        for (int v = idx; v < N4; v += stride) {
            int flat = v << 2;                   // att is (B, T, L)
            int b  = flat >> 19;
            int t  = (flat >> 8) & (Tn - 1);
            int l0 = flat & (Ln - 1);
            int ili = ilen[b];
            int oli = olen[b];
            if (t >= oli) continue;
            float il = (float)ili, ol = (float)oli;
            float tf = (float)t / ol;
            float4 a = reinterpret_cast<const float4*>(att)[v];
            #pragma unroll
            for (int c = 0; c < 4; ++c) {
                int l = l0 + c;
                float av = (c == 0) ? a.x : (c == 1) ? a.y : (c == 2) ? a.z : a.w;
                if (l < ili) {
                    float d = (float)l / il - tf;
                    acc += (1.f - __expf(-d * d * 3.125f)) * av;
                }
            }
        }
        for (int off = 32; off > 0; off >>= 1) acc += __shfl_down(acc, off, 64);
        __shared__ float sw[4];
        if ((tid & 63) == 0) sw[tid >> 6] = acc;
        __syncthreads();
        if (tid == 0) partial[bid - 4096] = (sw[0] + sw[1]) + (sw[2] + sw[3]);
    }
}

// ---------------- deterministic final loss reduce ----------------
__global__ void k_loss_final(const float* __restrict__ partial, int np,
                             const int* __restrict__ olen,
                             float* __restrict__ out) {
    int tid = threadIdx.x;
    float acc = 0.f;
    for (int i = tid; i < np; i += 256) acc += partial[i];
    for (int off = 32; off > 0; off >>= 1) acc += __shfl_down(acc, off, 64);
    __shared__ float sw[4];
    if ((tid & 63) == 0) sw[tid >> 6] = acc;
    __syncthreads();
    if (tid == 0) {
        float tot = (sw[0] + sw[1]) + (sw[2] + sw[3]);
        int so = 0;
        for (int i = 0; i < Bn; ++i) so += olen[i];
        out[0] = tot / (float)so;
    }
}

// ---------------- Viterbi forward: global_load_lds pipeline ----------------
__device__ inline void gl_lds16(const float* g, float* l) {
    __builtin_amdgcn_global_load_lds(
        (const __attribute__((address_space(1))) unsigned int*)(g),
        (__attribute__((address_space(3))) unsigned int*)(l),
        16, 0, 0);
}

#define WAITV(N) { asm volatile("s_waitcnt vmcnt(" #N ")" ::: "memory"); \
                   __builtin_amdgcn_sched_barrier(0); }

// chunk c covers t = 16c+1 .. 16c+16 ; wsT row (t-1) = 16c+j
#define ISSUE(C) { \
    const float* gsrc = wbase + (size_t)(C) * 4096 + (lane << 2); \
    float* ldst = buf + ((C) & 3) * 4096; \
    _Pragma("unroll") \
    for (int j = 0; j < 16; ++j) gl_lds16(gsrc + j * 256, ldst + j * 256); }

// S = t - 64m (1..64), compile-time; J = LDS step slot (0..15), compile-time
#define STEPS(S, J) { \
    float4 q = *reinterpret_cast<const float4*>(bp + (J) * 256 + (lane << 2)); \
    float c0 = fmaxf(pv0, left) + q.x; \
    float c1 = fmaxf(pv1, pv0) + q.y; \
    float c2 = fmaxf(pv2, pv1) + q.z; \
    float c3 = fmaxf(pv3, pv2) + q.w; \
    float sv = __shfl(c3, src, 64); \
    uint32_t e0 = __float_as_uint(c0 - sv) >> 31; \
    uint32_t e1 = __float_as_uint(c1 - c0) >> 31; \
    uint32_t e2 = __float_as_uint(c2 - c1) >> 31; \
    uint32_t e3 = __float_as_uint(c3 - c2) >> 31; \
    if (((S) & 32) == 0) { \
        a0lo |= e0 << ((S) & 31); a1lo |= e1 << ((S) & 31); \
        a2lo |= e2 << ((S) & 31); a3lo |= e3 << ((S) & 31); \
    } else { \
        a0hi |= e0 << ((S) & 31); a1hi |= e1 << ((S) & 31); \
        a2hi |= e2 << ((S) & 31); a3hi |= e3 << ((S) & 31); \
    } \
    if ((S) == 63) { \
        bb[(size_t)(4 * lane + 0) * TB + m] = ((uint64_t)a0hi << 32) | a0lo; \
        bb[(size_t)(4 * lane + 1) * TB + m] = ((uint64_t)a1hi << 32) | a1lo; \
        bb[(size_t)(4 * lane + 2) * TB + m] = ((uint64_t)a2hi << 32) | a2lo; \
        bb[(size_t)(4 * lane + 3) * TB + m] = ((uint64_t)a3hi << 32) | a3lo; \
        a0lo = a0hi = a1lo = a1hi = a2lo = a2hi = a3lo = a3hi = 0; \
    } \
    left = isl0 ? NEG : sv; \
    pv0 = c0; pv1 = c1; pv2 = c2; pv3 = c3; }

#define COMP16(I) { \
    const float* bp = buf + ((4 * m + (I)) & 3) * 4096; \
    STEPS(16*(I)+ 1, 0)  STEPS(16*(I)+ 2, 1)  STEPS(16*(I)+ 3, 2)  STEPS(16*(I)+ 4, 3) \
    STEPS(16*(I)+ 5, 4)  STEPS(16*(I)+ 6, 5)  STEPS(16*(I)+ 7, 6)  STEPS(16*(I)+ 8, 7) \
    STEPS(16*(I)+ 9, 8)  STEPS(16*(I)+10, 9)  STEPS(16*(I)+11,10)  STEPS(16*(I)+12,11) \
    STEPS(16*(I)+13,12)  STEPS(16*(I)+14,13)  STEPS(16*(I)+15,14)  STEPS(16*(I)+16,15) }

__global__ void __launch_bounds__(64, 1) k_forward3(const float* __restrict__ logp,
                                                    const float* __restrict__ wsT,
                                                    uint64_t* __restrict__ bits) {
    __shared__ float buf[4 * 16 * 256];   // 64 KB ring: 4 buffers x 16 steps x 1KB
    int b = blockIdx.x;
    int lane = threadIdx.x;
    int src = (lane + 63) & 63;
    bool isl0 = (lane == 0);
    uint64_t* bb = bits + (size_t)b * (Ln * TB);
    const float* wbase = wsT + (size_t)b * WST_BSTRIDE;

    float pv0, pv1, pv2, pv3, left;
    uint32_t a0lo = 0, a0hi = 0, a1lo = 0, a1hi = 0;
    uint32_t a2lo = 0, a2hi = 0, a3lo = 0, a3hi = 0;

    // peeled t = 0: init row0 = logp[b,0,0], others NEG; seed bit 0 of word 0
    {
        float lp00 = logp[(size_t)b * (Ln * Tn)];
        float n0 = isl0 ? lp00 : NEG;
        float n1 = NEG, n2 = NEG, n3 = NEG;
        float sv = __shfl(n3, src, 64);
        a0lo |= __float_as_uint(n0 - sv) >> 31;
        a1lo |= __float_as_uint(n1 - n0) >> 31;
        a2lo |= __float_as_uint(n2 - n1) >> 31;
        a3lo |= __float_as_uint(n3 - n2) >> 31;
        left = NEG;
        pv0 = n0; pv1 = n1; pv2 = n2; pv3 = n3;
    }

    ISSUE(0) ISSUE(1) ISSUE(2)            // 48 loads in flight

    for (int m = 0; m < 31; ++m) {
        int cb = 4 * m;
        WAITV(32) COMP16(0) ISSUE(cb + 3)
        WAITV(32) COMP16(1) ISSUE(cb + 4)
        WAITV(32) COMP16(2) ISSUE(cb + 5)
        WAITV(32) COMP16(3) ISSUE(cb + 6)
    }
    {   // m = 31 (chunks 124..127); step S=64 of COMP16(3) is t=2048 garbage (never flushed)
        int m = 31;
        WAITV(32) COMP16(0) ISSUE(127)
        WAITV(32) COMP16(1)
        WAITV(16) COMP16(2)
        WAITV(0)  COMP16(3)
    }
}

// ---------------- backtrack: LDS bits, 4-deep window walk -> per-row extents ----------------
__global__ void __launch_bounds__(64) k_backtrack3(const uint64_t* __restrict__ bits,
                                                   const int* __restrict__ ilen,
                                                   const int* __restrict__ olen,
                                                   int2* __restrict__ ext) {
    __shared__ uint64_t sb[Ln * TB];   // 64 KB
    int b = blockIdx.x, lane = threadIdx.x;
    #pragma unroll
    for (int i = 0; i < 4; ++i) ext[b * Ln + i * 64 + lane] = make_int2(1, 0);  // empty
    const ulonglong2* g = (const ulonglong2*)(bits + (size_t)b * (Ln * TB));
    ulonglong2* s2 = (ulonglong2*)sb;
    #pragma unroll
    for (int i = 0; i < 64; ++i) s2[i * 64 + lane] = g[i * 64 + lane];
    __syncthreads();
    if (lane != 0) return;

    int tl = ilen[b], ml = olen[b];
    int2* eb = ext + b * Ln;
    int r = tl - 1, hi = ml - 1, p = ml - 2;
    if (p < 0) { eb[r] = make_int2(0, hi); return; }
    int c = p >> 6;
    uint64_t w0 = sb[r * TB + c];
    uint64_t w1 = sb[(r > 0 ? r - 1 : 0) * TB + c];
    uint64_t w2 = sb[(r > 1 ? r - 2 : 0) * TB + c];
    uint64_t w3 = sb[(r > 2 ? r - 3 : 0) * TB + c];
    int vd = 3;
    while (true) {
        int pb = p & 63;
        uint64_t mask = (pb == 63) ? ~0ull : ((1ull << (pb + 1)) - 1ull);
        uint64_t m = w0 & mask;
        if (m == 0) {
            p = (p & ~63) - 1;
            if (p < 0) { eb[r] = make_int2(0, hi); break; }
            c = p >> 6;
            w0 = sb[r * TB + c];
            w1 = sb[(r > 0 ? r - 1 : 0) * TB + c];
            w2 = sb[(r > 1 ? r - 2 : 0) * TB + c];
            w3 = sb[(r > 2 ? r - 3 : 0) * TB + c];
            vd = 3;
        } else {
            int q = 63 - __builtin_clzll(m);
            int tq = (p & ~63) + q;
            eb[r] = make_int2(tq + 1, hi);
            r -= 1;
            if (r < 0) break;                   // saturation: remaining columns zero
            hi = tq;
            p = tq - 1;
            if (p < 0) { eb[r] = make_int2(0, hi); break; }
            w0 = w1; w1 = w2; w2 = w3; vd -= 1;
            int nc = p >> 6;
            if (nc != c || vd == 0) {
                c = nc;
                w0 = sb[r * TB + c];
                w1 = sb[(r > 0 ? r - 1 : 0) * TB + c];
                w2 = sb[(r > 1 ? r - 2 : 0) * TB + c];
                w3 = sb[(r > 2 ? r - 3 : 0) * TB + c];
                vd = 3;
            }
        }
    }
}

// ---------------- write full output from extents (replaces zero + scatter) ----------------
__global__ void k_fill(const int2* __restrict__ ext, float* __restrict__ out) {
    int idx = blockIdx.x * blockDim.x + threadIdx.x;
    const int total = Bn * Ln * (Tn / 4);          // 4,194,304 groups of 4 t's
    int stride = gridDim.x * blockDim.x;
    for (int i = idx; i < total; i += stride) {
        int row = i >> 9;                          // (b*256 + l)
        int t0 = (i & 511) << 2;
        int2 e = ext[row];
        float* p = out + 1 + ((size_t)row << 11) + t0;
        p[0] = (t0     >= e.x && t0     <= e.y) ? 1.f : 0.f;
        p[1] = (t0 + 1 >= e.x && t0 + 1 <= e.y) ? 1.f : 0.f;
        p[2] = (t0 + 2 >= e.x && t0 + 2 <= e.y) ? 1.f : 0.f;
        p[3] = (t0 + 3 >= e.x && t0 + 3 <= e.y) ? 1.f : 0.f;
    }
}

extern "C" void kernel_launch(void* const* d_in, const int* in_sizes, int n_in,
                              void* d_out, int out_size, void* d_ws, size_t ws_size,
                              hipStream_t stream) {
    const float* logp = (const float*)d_in[0];
    const float* att  = (const float*)d_in[1];
    const int* tlen   = (const int*)d_in[2];
    const int* mlen   = (const int*)d_in[3];
    float* out = (float*)d_out;
    uint64_t* bits = (uint64_t*)d_ws;                                   // 2 MB
    float* partial = (float*)((char*)d_ws + (size_t)Bn * Ln * TB * 8);  // +4 KB
    int2* ext = (int2*)((char*)d_ws + (size_t)Bn * Ln * TB * 8 + 4096); // +64 KB

    // 1) transpose logp into d_out scratch + loss partials
    k_trans_loss<<<5120, 256, 0, stream>>>(logp, att, tlen, mlen, out, partial);
    // 2) forward DP: LDS-staged pipeline, bits -> ws
    k_forward3<<<Bn, 64, 0, stream>>>(logp, out, bits);
    // 3) backtrack -> per-row run extents
    k_backtrack3<<<Bn, 64, 0, stream>>>(bits, tlen, mlen, ext);
    // 4) write full 0/1 output from extents (overwrites scratch)
    k_fill<<<2048, 256, 0, stream>>>(ext, out);
    // 5) final loss reduce -> out[0]
    k_loss_final<<<1, 256, 0, stream>>>(partial, 1024, mlen, out);
}

// Round 4
// 237.812 us; speedup vs baseline: 2.0194x; 1.2512x over previous
//
#include <hip/hip_runtime.h>
#include <cstdint>

#define NEG (-1e12f)
constexpr int Bn = 32, Ln = 256, Tn = 2048;
constexpr int TB = Tn / 64;                 // 32 uint64 words of t-bits per text row
constexpr int WST_BSTRIDE = (Tn - 1) * Ln;  // 524032 floats per batch in wsT (t>=1 only)

// ---------------- fused transpose + loss partials ----------------
__global__ void k_trans_loss(const float* __restrict__ logp,
                             const float* __restrict__ att,
                             const int* __restrict__ ilen,
                             const int* __restrict__ olen,
                             float* __restrict__ wsT,
                             float* __restrict__ partial) {
    __shared__ float tile[64 * 68];
    int bid = blockIdx.x;
    int tid = threadIdx.x;
    if (bid < 4096) {
        int b = bid >> 7, rest = bid & 127;
        int lt = rest >> 5, tt = rest & 31;      // 4 l-tiles x 32 t-tiles of 64x64
        const float* src = logp + ((size_t)b * Ln + lt * 64) * Tn + (size_t)tt * 64;
        int lr = tid >> 4, tc4 = (tid & 15) * 4;
        #pragma unroll
        for (int pass = 0; pass < 4; ++pass) {
            int l_loc = pass * 16 + lr;
            float4 v = *(const float4*)(src + (size_t)l_loc * Tn + tc4);
            *(float4*)(&tile[l_loc * 68 + tc4]) = v;
        }
        __syncthreads();
        float* dst = wsT + (size_t)b * WST_BSTRIDE + lt * 64;
        #pragma unroll
        for (int pass = 0; pass < 4; ++pass) {
            int t_loc = pass * 16 + lr;
            float4 v;
            v.x = tile[(tc4 + 0) * 68 + t_loc];
            v.y = tile[(tc4 + 1) * 68 + t_loc];
            v.z = tile[(tc4 + 2) * 68 + t_loc];
            v.w = tile[(tc4 + 3) * 68 + t_loc];
            int tg = tt * 64 + t_loc;
            if (tg >= 1) *(float4*)(dst + (size_t)(tg - 1) * Ln + tc4) = v;
        }
    } else {
        const int N4 = Bn * Tn * Ln / 4;
        int idx = (bid - 4096) * blockDim.x + tid;
        int stride = 1024 * 256;
        float acc = 0.f;
        for (int v = idx; v < N4; v += stride) {
            int flat = v << 2;                   // att is (B, T, L)
            int b  = flat >> 19;
            int t  = (flat >> 8) & (Tn - 1);
            int l0 = flat & (Ln - 1);
            int ili = ilen[b];
            int oli = olen[b];
            if (t >= oli) continue;
            float il = (float)ili, ol = (float)oli;
            float tf = (float)t / ol;
            float4 a = reinterpret_cast<const float4*>(att)[v];
            #pragma unroll
            for (int c = 0; c < 4; ++c) {
                int l = l0 + c;
                float av = (c == 0) ? a.x : (c == 1) ? a.y : (c == 2) ? a.z : a.w;
                if (l < ili) {
                    float d = (float)l / il - tf;
                    acc += (1.f - __expf(-d * d * 3.125f)) * av;
                }
            }
        }
        for (int off = 32; off > 0; off >>= 1) acc += __shfl_down(acc, off, 64);
        __shared__ float sw[4];
        if ((tid & 63) == 0) sw[tid >> 6] = acc;
        __syncthreads();
        if (tid == 0) partial[bid - 4096] = (sw[0] + sw[1]) + (sw[2] + sw[3]);
    }
}

// ---------------- Viterbi forward: gl_lds staging + DPP neighbor + reg pipeline ----------------
__device__ inline void gl_lds16(const float* g, float* l) {
    __builtin_amdgcn_global_load_lds(
        (const __attribute__((address_space(1))) unsigned int*)(g),
        (__attribute__((address_space(3))) unsigned int*)(l),
        16, 0, 0);
}

// lane i <- lane (i-1)&63  (wave_ror:1) : torch-wrap neighbor for the bit compare
__device__ inline float dpp_ror1(float x) {
    int xi = __float_as_int(x);
    return __int_as_float(__builtin_amdgcn_update_dpp(xi, xi, 0x13C, 0xF, 0xF, false));
}
// lane i <- lane i-1, lane 0 <- old  (wave_shr:1) : DP 'left' input directly
__device__ inline float dpp_shr1(float x, float old) {
    return __int_as_float(__builtin_amdgcn_update_dpp(
        __float_as_int(old), __float_as_int(x), 0x138, 0xF, 0xF, false));
}

#define WAITV(N) { asm volatile("s_waitcnt vmcnt(" #N ")" ::: "memory"); \
                   __builtin_amdgcn_sched_barrier(0); }

// chunk c covers t = 16c+1 .. 16c+16 ; wsT row (t-1) = 16c+j ; LDS buffer = c & 3
#define ISSUE(C) { \
    const float* gsrc = wbase + (size_t)(C) * 4096 + (lane << 2); \
    float* ldst = buf + ((C) & 3) * 4096; \
    _Pragma("unroll") \
    for (int j = 0; j < 16; ++j) gl_lds16(gsrc + j * 256, ldst + j * 256); }

// S = t - 64m (1..64) compile-time; Q = preloaded float4 for this step
#define STEPS(S, Q) { \
    float c0 = fmaxf(pv0, left) + (Q).x; \
    float c1 = fmaxf(pv1, pv0) + (Q).y; \
    float c2 = fmaxf(pv2, pv1) + (Q).z; \
    float c3 = fmaxf(pv3, pv2) + (Q).w; \
    float sv = dpp_ror1(c3); \
    left = dpp_shr1(c3, negc); \
    uint32_t e0 = __float_as_uint(c0 - sv) >> 31; \
    uint32_t e1 = __float_as_uint(c1 - c0) >> 31; \
    uint32_t e2 = __float_as_uint(c2 - c1) >> 31; \
    uint32_t e3 = __float_as_uint(c3 - c2) >> 31; \
    if (((S) & 32) == 0) { \
        a0lo |= e0 << ((S) & 31); a1lo |= e1 << ((S) & 31); \
        a2lo |= e2 << ((S) & 31); a3lo |= e3 << ((S) & 31); \
    } else { \
        a0hi |= e0 << ((S) & 31); a1hi |= e1 << ((S) & 31); \
        a2hi |= e2 << ((S) & 31); a3hi |= e3 << ((S) & 31); \
    } \
    if ((S) == 63) { \
        bb[(size_t)(4 * lane + 0) * TB + m] = ((uint64_t)a0hi << 32) | a0lo; \
        bb[(size_t)(4 * lane + 1) * TB + m] = ((uint64_t)a1hi << 32) | a1lo; \
        bb[(size_t)(4 * lane + 2) * TB + m] = ((uint64_t)a2hi << 32) | a2lo; \
        bb[(size_t)(4 * lane + 3) * TB + m] = ((uint64_t)a3hi << 32) | a3lo; \
        a0lo = a0hi = a1lo = a1hi = a2lo = a2hi = a3lo = a3hi = 0; \
    } \
    pv0 = c0; pv1 = c1; pv2 = c2; pv3 = c3; }

#define LDQ(J) (*reinterpret_cast<const float4*>(bp + (J) * 256))

// 16 steps, 4-deep rotating register prefetch of the LDS rows
#define COMP16(I) { \
    const float* bp = buf + (I) * 4096 + (lane << 2); \
    float4 qq0 = LDQ(0), qq1 = LDQ(1), qq2 = LDQ(2), qq3 = LDQ(3); \
    STEPS(16*(I)+ 1, qq0) qq0 = LDQ( 4); \
    STEPS(16*(I)+ 2, qq1) qq1 = LDQ( 5); \
    STEPS(16*(I)+ 3, qq2) qq2 = LDQ( 6); \
    STEPS(16*(I)+ 4, qq3) qq3 = LDQ( 7); \
    STEPS(16*(I)+ 5, qq0) qq0 = LDQ( 8); \
    STEPS(16*(I)+ 6, qq1) qq1 = LDQ( 9); \
    STEPS(16*(I)+ 7, qq2) qq2 = LDQ(10); \
    STEPS(16*(I)+ 8, qq3) qq3 = LDQ(11); \
    STEPS(16*(I)+ 9, qq0) qq0 = LDQ(12); \
    STEPS(16*(I)+10, qq1) qq1 = LDQ(13); \
    STEPS(16*(I)+11, qq2) qq2 = LDQ(14); \
    STEPS(16*(I)+12, qq3) qq3 = LDQ(15); \
    STEPS(16*(I)+13, qq0) \
    STEPS(16*(I)+14, qq1) \
    STEPS(16*(I)+15, qq2) \
    STEPS(16*(I)+16, qq3) }

__global__ void __launch_bounds__(64, 1) k_forward4(const float* __restrict__ logp,
                                                    const float* __restrict__ wsT,
                                                    uint64_t* __restrict__ bits) {
    __shared__ __align__(16) float buf[4 * 16 * 256];   // 64 KB ring
    int b = blockIdx.x;
    int lane = threadIdx.x;
    uint64_t* bb = bits + (size_t)b * (Ln * TB);
    const float* wbase = wsT + (size_t)b * WST_BSTRIDE;
    const float negc = NEG;

    float pv0, pv1, pv2, pv3, left;
    uint32_t a0lo = 0, a0hi = 0, a1lo = 0, a1hi = 0;
    uint32_t a2lo = 0, a2hi = 0, a3lo = 0, a3hi = 0;

    // peeled t = 0: row0 = logp[b,0,0], others NEG; seed bit 0 of word 0
    {
        float lp00 = logp[(size_t)b * (Ln * Tn)];
        float n0 = (lane == 0) ? lp00 : NEG;
        float n1 = NEG, n2 = NEG, n3 = NEG;
        float sv = dpp_ror1(n3);
        a0lo |= __float_as_uint(n0 - sv) >> 31;
        a1lo |= __float_as_uint(n1 - n0) >> 31;
        a2lo |= __float_as_uint(n2 - n1) >> 31;
        a3lo |= __float_as_uint(n3 - n2) >> 31;
        left = NEG;
        pv0 = n0; pv1 = n1; pv2 = n2; pv3 = n3;
    }

    ISSUE(0) ISSUE(1) ISSUE(2)            // 48 loads in flight

    for (int m = 0; m < 31; ++m) {
        int cb = 4 * m;
        WAITV(32) COMP16(0) ISSUE(cb + 3)
        WAITV(32) COMP16(1) ISSUE(cb + 4)
        WAITV(32) COMP16(2) ISSUE(cb + 5)
        WAITV(32) COMP16(3) ISSUE(cb + 6)
    }
    {   // m = 31 (chunks 124..127); step S=64 of COMP16(3) is t=2048 garbage (never flushed)
        int m = 31;
        WAITV(32) COMP16(0) ISSUE(127)
        WAITV(32) COMP16(1)
        WAITV(16) COMP16(2)
        WAITV(0)  COMP16(3)
    }
}

// ---------------- backtrack: LDS bits, 4-deep window walk -> per-row extents ----------------
__global__ void __launch_bounds__(64) k_backtrack3(const uint64_t* __restrict__ bits,
                                                   const int* __restrict__ ilen,
                                                   const int* __restrict__ olen,
                                                   int2* __restrict__ ext) {
    __shared__ uint64_t sb[Ln * TB];   // 64 KB
    int b = blockIdx.x, lane = threadIdx.x;
    #pragma unroll
    for (int i = 0; i < 4; ++i) ext[b * Ln + i * 64 + lane] = make_int2(1, 0);  // empty
    const ulonglong2* g = (const ulonglong2*)(bits + (size_t)b * (Ln * TB));
    ulonglong2* s2 = (ulonglong2*)sb;
    #pragma unroll
    for (int i = 0; i < 64; ++i) s2[i * 64 + lane] = g[i * 64 + lane];
    __syncthreads();
    if (lane != 0) return;

    int tl = ilen[b], ml = olen[b];
    int2* eb = ext + b * Ln;
    int r = tl - 1, hi = ml - 1, p = ml - 2;
    if (p < 0) { eb[r] = make_int2(0, hi); return; }
    int c = p >> 6;
    uint64_t w0 = sb[r * TB + c];
    uint64_t w1 = sb[(r > 0 ? r - 1 : 0) * TB + c];
    uint64_t w2 = sb[(r > 1 ? r - 2 : 0) * TB + c];
    uint64_t w3 = sb[(r > 2 ? r - 3 : 0) * TB + c];
    int vd = 3;
    while (true) {
        int pb = p & 63;
        uint64_t mask = (pb == 63) ? ~0ull : ((1ull << (pb + 1)) - 1ull);
        uint64_t m = w0 & mask;
        if (m == 0) {
            p = (p & ~63) - 1;
            if (p < 0) { eb[r] = make_int2(0, hi); break; }
            c = p >> 6;
            w0 = sb[r * TB + c];
            w1 = sb[(r > 0 ? r - 1 : 0) * TB + c];
            w2 = sb[(r > 1 ? r - 2 : 0) * TB + c];
            w3 = sb[(r > 2 ? r - 3 : 0) * TB + c];
            vd = 3;
        } else {
            int q = 63 - __builtin_clzll(m);
            int tq = (p & ~63) + q;
            eb[r] = make_int2(tq + 1, hi);
            r -= 1;
            if (r < 0) break;                   // saturation: remaining columns zero
            hi = tq;
            p = tq - 1;
            if (p < 0) { eb[r] = make_int2(0, hi); break; }
            w0 = w1; w1 = w2; w2 = w3; vd -= 1;
            int nc = p >> 6;
            if (nc != c || vd == 0) {
                c = nc;
                w0 = sb[r * TB + c];
                w1 = sb[(r > 0 ? r - 1 : 0) * TB + c];
                w2 = sb[(r > 1 ? r - 2 : 0) * TB + c];
                w3 = sb[(r > 2 ? r - 3 : 0) * TB + c];
                vd = 3;
            }
        }
    }
}

// ---------------- aligned-float4 fill from extents + fused final loss reduce ----------------
__global__ void k_fill(const int2* __restrict__ ext, const float* __restrict__ partial,
                       const int* __restrict__ olen, float* __restrict__ out) {
    const int NG = (Bn * Ln * Tn) / 4;          // 4,194,304 aligned float4 groups
    int idx = blockIdx.x * blockDim.x + threadIdx.x;
    int stride = gridDim.x * blockDim.x;
    for (int i = idx; i < NG; i += stride) {
        if (i == 0) {
            int2 e = ext[0];                     // out[1..3] = align f=0..2 (row 0)
            out[1] = (0 >= e.x && 0 <= e.y) ? 1.f : 0.f;
            out[2] = (1 >= e.x && 1 <= e.y) ? 1.f : 0.f;
            out[3] = (2 >= e.x && 2 <= e.y) ? 1.f : 0.f;
            int2 el = ext[Bn * Ln - 1];          // last element: row 8191, t=2047
            out[(size_t)Bn * Ln * Tn] = (2047 >= el.x && 2047 <= el.y) ? 1.f : 0.f;
            continue;
        }
        int f0 = 4 * i - 1;                      // align flat index of out[4i]
        int r0 = f0 >> 11;
        int t0 = f0 & 2047;
        int2 e0 = ext[r0];
        float4 v;
        if (t0 != 2047) {                        // all 4 in row r0
            v.x = (t0     >= e0.x && t0     <= e0.y) ? 1.f : 0.f;
            v.y = (t0 + 1 >= e0.x && t0 + 1 <= e0.y) ? 1.f : 0.f;
            v.z = (t0 + 2 >= e0.x && t0 + 2 <= e0.y) ? 1.f : 0.f;
            v.w = (t0 + 3 >= e0.x && t0 + 3 <= e0.y) ? 1.f : 0.f;
        } else {                                 // crosses into row r0+1 (t=0,1,2)
            int2 e1 = ext[r0 + 1];
            v.x = (2047 >= e0.x && 2047 <= e0.y) ? 1.f : 0.f;
            v.y = (0 >= e1.x && 0 <= e1.y) ? 1.f : 0.f;
            v.z = (1 >= e1.x && 1 <= e1.y) ? 1.f : 0.f;
            v.w = (2 >= e1.x && 2 <= e1.y) ? 1.f : 0.f;
        }
        *reinterpret_cast<float4*>(out + (size_t)4 * i) = v;
    }
    if (blockIdx.x == 0) {                       // fused deterministic loss reduce
        int tid = threadIdx.x;
        float acc = 0.f;
        for (int i = tid; i < 1024; i += 256) acc += partial[i];
        for (int off = 32; off > 0; off >>= 1) acc += __shfl_down(acc, off, 64);
        __shared__ float sw[4];
        if ((tid & 63) == 0) sw[tid >> 6] = acc;
        __syncthreads();
        if (tid == 0) {
            float tot = (sw[0] + sw[1]) + (sw[2] + sw[3]);
            int so = 0;
            for (int i = 0; i < Bn; ++i) so += olen[i];
            out[0] = tot / (float)so;
        }
    }
}

extern "C" void kernel_launch(void* const* d_in, const int* in_sizes, int n_in,
                              void* d_out, int out_size, void* d_ws, size_t ws_size,
                              hipStream_t stream) {
    const float* logp = (const float*)d_in[0];
    const float* att  = (const float*)d_in[1];
    const int* tlen   = (const int*)d_in[2];
    const int* mlen   = (const int*)d_in[3];
    float* out = (float*)d_out;
    uint64_t* bits = (uint64_t*)d_ws;                                   // 2 MB
    float* partial = (float*)((char*)d_ws + (size_t)Bn * Ln * TB * 8);  // +4 KB
    int2* ext = (int2*)((char*)d_ws + (size_t)Bn * Ln * TB * 8 + 4096); // +64 KB

    // 1) transpose logp into d_out scratch + loss partials
    k_trans_loss<<<5120, 256, 0, stream>>>(logp, att, tlen, mlen, out, partial);
    // 2) forward DP: LDS-staged pipeline + DPP neighbor, bits -> ws
    k_forward4<<<Bn, 64, 0, stream>>>(logp, out, bits);
    // 3) backtrack -> per-row run extents
    k_backtrack3<<<Bn, 64, 0, stream>>>(bits, tlen, mlen, ext);
    // 4) write full 0/1 output from extents + final loss reduce (overwrites scratch)
    k_fill<<<2048, 256, 0, stream>>>(ext, partial, mlen, out);
}

// Round 5
// 218.709 us; speedup vs baseline: 2.1958x; 1.0873x over previous
//
#include <hip/hip_runtime.h>
#include <cstdint>

#define NEG (-1e12f)
constexpr int Bn = 32, Ln = 256, Tn = 2048;
constexpr int TB = Tn / 64;                 // 32 uint64 words of t-bits per text row
constexpr int WST_BSTRIDE = (Tn - 1) * Ln;  // 524032 floats per batch in wsT (t>=1 only)

// ---------------- fused transpose + loss partials ----------------
__global__ void k_trans_loss(const float* __restrict__ logp,
                             const float* __restrict__ att,
                             const int* __restrict__ ilen,
                             const int* __restrict__ olen,
                             float* __restrict__ wsT,
                             float* __restrict__ partial) {
    __shared__ float tile[64 * 68];
    int bid = blockIdx.x;
    int tid = threadIdx.x;
    if (bid < 4096) {
        int b = bid >> 7, rest = bid & 127;
        int lt = rest >> 5, tt = rest & 31;      // 4 l-tiles x 32 t-tiles of 64x64
        const float* src = logp + ((size_t)b * Ln + lt * 64) * Tn + (size_t)tt * 64;
        int lr = tid >> 4, tc4 = (tid & 15) * 4;
        #pragma unroll
        for (int pass = 0; pass < 4; ++pass) {
            int l_loc = pass * 16 + lr;
            float4 v = *(const float4*)(src + (size_t)l_loc * Tn + tc4);
            *(float4*)(&tile[l_loc * 68 + tc4]) = v;
        }
        __syncthreads();
        float* dst = wsT + (size_t)b * WST_BSTRIDE + lt * 64;
        #pragma unroll
        for (int pass = 0; pass < 4; ++pass) {
            int t_loc = pass * 16 + lr;
            float4 v;
            v.x = tile[(tc4 + 0) * 68 + t_loc];
            v.y = tile[(tc4 + 1) * 68 + t_loc];
            v.z = tile[(tc4 + 2) * 68 + t_loc];
            v.w = tile[(tc4 + 3) * 68 + t_loc];
            int tg = tt * 64 + t_loc;
            if (tg >= 1) *(float4*)(dst + (size_t)(tg - 1) * Ln + tc4) = v;
        }
    } else {
        const int N4 = Bn * Tn * Ln / 4;
        int idx = (bid - 4096) * blockDim.x + tid;
        int stride = 1024 * 256;
        float acc = 0.f;
        for (int v = idx; v < N4; v += stride) {
            int flat = v << 2;                   // att is (B, T, L)
            int b  = flat >> 19;
            int t  = (flat >> 8) & (Tn - 1);
            int l0 = flat & (Ln - 1);
            int ili = ilen[b];
            int oli = olen[b];
            if (t >= oli) continue;
            float il = (float)ili, ol = (float)oli;
            float tf = (float)t / ol;
            float4 a = reinterpret_cast<const float4*>(att)[v];
            #pragma unroll
            for (int c = 0; c < 4; ++c) {
                int l = l0 + c;
                float av = (c == 0) ? a.x : (c == 1) ? a.y : (c == 2) ? a.z : a.w;
                if (l < ili) {
                    float d = (float)l / il - tf;
                    acc += (1.f - __expf(-d * d * 3.125f)) * av;
                }
            }
        }
        for (int off = 32; off > 0; off >>= 1) acc += __shfl_down(acc, off, 64);
        __shared__ float sw[4];
        if ((tid & 63) == 0) sw[tid >> 6] = acc;
        __syncthreads();
        if (tid == 0) partial[bid - 4096] = (sw[0] + sw[1]) + (sw[2] + sw[3]);
    }
}

// ---------------- Viterbi forward: gl_lds staging + DPP + 8-deep reg prefetch ----------------
__device__ inline void gl_lds16(const float* g, float* l) {
    __builtin_amdgcn_global_load_lds(
        (const __attribute__((address_space(1))) unsigned int*)(g),
        (__attribute__((address_space(3))) unsigned int*)(l),
        16, 0, 0);
}

// lane i <- lane (i-1)&63  (wave_ror:1) : torch-wrap neighbor for the bit compare
__device__ inline float dpp_ror1(float x) {
    int xi = __float_as_int(x);
    return __int_as_float(__builtin_amdgcn_update_dpp(xi, xi, 0x13C, 0xF, 0xF, false));
}
// lane i <- lane i-1, lane 0 <- old  (wave_shr:1) : DP 'left' input directly
__device__ inline float dpp_shr1(float x, float old) {
    return __int_as_float(__builtin_amdgcn_update_dpp(
        __float_as_int(old), __float_as_int(x), 0x138, 0xF, 0xF, false));
}

#define WAITV(N) { asm volatile("s_waitcnt vmcnt(" #N ")" ::: "memory"); \
                   __builtin_amdgcn_sched_barrier(0); }

// chunk c covers t = 16c+1 .. 16c+16 ; wsT row (t-1) = 16c+j ; LDS buffer = c & 3
#define ISSUE(C) { \
    const float* gsrc = wbase + (size_t)(C) * 4096 + (lane << 2); \
    float* ldst = buf + ((C) & 3) * 4096; \
    _Pragma("unroll") \
    for (int j = 0; j < 16; ++j) gl_lds16(gsrc + j * 256, ldst + j * 256); }

#define LDQB(BI, ROW) (*reinterpret_cast<const float4*>(buf + (BI) * 4096 + (ROW) * 256 + (lane << 2)))

// S = t - 64m (1..64) compile-time; Q = preloaded float4 for this step
// c3 computed first so the DPP reads have VALU between write and read.
#define STEPS(S, Q) { \
    float c3 = fmaxf(pv3, pv2) + (Q).w; \
    float c2 = fmaxf(pv2, pv1) + (Q).z; \
    float c1 = fmaxf(pv1, pv0) + (Q).y; \
    float c0 = fmaxf(pv0, left) + (Q).x; \
    float sv = dpp_ror1(c3); \
    left = dpp_shr1(c3, negc); \
    uint32_t e0 = __float_as_uint(c0 - sv) >> 31; \
    uint32_t e1 = __float_as_uint(c1 - c0) >> 31; \
    uint32_t e2 = __float_as_uint(c2 - c1) >> 31; \
    uint32_t e3 = __float_as_uint(c3 - c2) >> 31; \
    if (((S) & 32) == 0) { \
        a0lo |= e0 << ((S) & 31); a1lo |= e1 << ((S) & 31); \
        a2lo |= e2 << ((S) & 31); a3lo |= e3 << ((S) & 31); \
    } else { \
        a0hi |= e0 << ((S) & 31); a1hi |= e1 << ((S) & 31); \
        a2hi |= e2 << ((S) & 31); a3hi |= e3 << ((S) & 31); \
    } \
    if ((S) == 63) { \
        bb[(size_t)(4 * lane + 0) * TB + m] = ((uint64_t)a0hi << 32) | a0lo; \
        bb[(size_t)(4 * lane + 1) * TB + m] = ((uint64_t)a1hi << 32) | a1lo; \
        bb[(size_t)(4 * lane + 2) * TB + m] = ((uint64_t)a2hi << 32) | a2lo; \
        bb[(size_t)(4 * lane + 3) * TB + m] = ((uint64_t)a3hi << 32) | a3lo; \
        a0lo = a0hi = a1lo = a1hi = a2lo = a2hi = a3lo = a3hi = 0; \
    } \
    pv0 = c0; pv1 = c1; pv2 = c2; pv3 = c3; }

// 16 steps of sub-chunk I (chunk c = 4m+I, buffer I); 8-deep rotating prefetch
// crossing into buffer (I+1)&3 for the next chunk's rows 0..7.
#define COMP16(I) { \
    STEPS(16*(I)+ 1, qq0) qq0 = LDQB((I), 8); \
    STEPS(16*(I)+ 2, qq1) qq1 = LDQB((I), 9); \
    STEPS(16*(I)+ 3, qq2) qq2 = LDQB((I),10); \
    STEPS(16*(I)+ 4, qq3) qq3 = LDQB((I),11); \
    STEPS(16*(I)+ 5, qq4) qq4 = LDQB((I),12); \
    STEPS(16*(I)+ 6, qq5) qq5 = LDQB((I),13); \
    STEPS(16*(I)+ 7, qq6) qq6 = LDQB((I),14); \
    STEPS(16*(I)+ 8, qq7) qq7 = LDQB((I),15); \
    STEPS(16*(I)+ 9, qq0) qq0 = LDQB(((I)+1)&3, 0); \
    STEPS(16*(I)+10, qq1) qq1 = LDQB(((I)+1)&3, 1); \
    STEPS(16*(I)+11, qq2) qq2 = LDQB(((I)+1)&3, 2); \
    STEPS(16*(I)+12, qq3) qq3 = LDQB(((I)+1)&3, 3); \
    STEPS(16*(I)+13, qq4) qq4 = LDQB(((I)+1)&3, 4); \
    STEPS(16*(I)+14, qq5) qq5 = LDQB(((I)+1)&3, 5); \
    STEPS(16*(I)+15, qq6) qq6 = LDQB(((I)+1)&3, 6); \
    STEPS(16*(I)+16, qq7) qq7 = LDQB(((I)+1)&3, 7); }

__global__ void __launch_bounds__(64, 1) k_forward5(const float* __restrict__ logp,
                                                    const float* __restrict__ wsT,
                                                    uint64_t* __restrict__ bits) {
    __shared__ __align__(16) float buf[4 * 16 * 256];   // 64 KB ring
    int b = blockIdx.x;
    int lane = threadIdx.x;
    uint64_t* bb = bits + (size_t)b * (Ln * TB);
    const float* wbase = wsT + (size_t)b * WST_BSTRIDE;
    const float negc = NEG;

    float pv0, pv1, pv2, pv3, left;
    uint32_t a0lo = 0, a0hi = 0, a1lo = 0, a1hi = 0;
    uint32_t a2lo = 0, a2hi = 0, a3lo = 0, a3hi = 0;

    // peeled t = 0: row0 = logp[b,0,0], others NEG; seed bit 0 of word 0
    {
        float lp00 = logp[(size_t)b * (Ln * Tn)];
        float n0 = (lane == 0) ? lp00 : NEG;
        float n1 = NEG, n2 = NEG, n3 = NEG;
        float sv = dpp_ror1(n3);
        a0lo |= __float_as_uint(n0 - sv) >> 31;
        a1lo |= __float_as_uint(n1 - n0) >> 31;
        a2lo |= __float_as_uint(n2 - n1) >> 31;
        a3lo |= __float_as_uint(n3 - n2) >> 31;
        left = NEG;
        pv0 = n0; pv1 = n1; pv2 = n2; pv3 = n3;
    }

    ISSUE(0) ISSUE(1) ISSUE(2)            // 48 loads in flight
    WAITV(16)                             // chunks 0,1 landed; chunk 2 outstanding

    float4 qq0 = LDQB(0, 0), qq1 = LDQB(0, 1), qq2 = LDQB(0, 2), qq3 = LDQB(0, 3);
    float4 qq4 = LDQB(0, 4), qq5 = LDQB(0, 5), qq6 = LDQB(0, 6), qq7 = LDQB(0, 7);

    // invariant at head of sub-chunk c: chunks <= c+1 landed, chunk c+2 in flight
    for (int m = 0; m < 31; ++m) {
        int cb = 4 * m;
        ISSUE(cb + 3) COMP16(0) WAITV(16)
        ISSUE(cb + 4) COMP16(1) WAITV(16)
        ISSUE(cb + 5) COMP16(2) WAITV(16)
        ISSUE(cb + 6) COMP16(3) WAITV(16)
    }
    {   // m = 31: chunks 124..127; no out-of-range ISSUEs.
        int m = 31;
        ISSUE(127) COMP16(0) WAITV(16)
        COMP16(1) WAITV(0)      // drain chunk 127 before its rows are prefetched
        COMP16(2)
        COMP16(3)               // j>=8 prefetches read stale buffer 0: never consumed
    }
}

// ---------------- backtrack: LDS bits, 4-deep window walk -> per-row extents ----------------
__global__ void __launch_bounds__(64) k_backtrack3(const uint64_t* __restrict__ bits,
                                                   const int* __restrict__ ilen,
                                                   const int* __restrict__ olen,
                                                   int2* __restrict__ ext) {
    __shared__ uint64_t sb[Ln * TB];   // 64 KB
    int b = blockIdx.x, lane = threadIdx.x;
    #pragma unroll
    for (int i = 0; i < 4; ++i) ext[b * Ln + i * 64 + lane] = make_int2(1, 0);  // empty
    const ulonglong2* g = (const ulonglong2*)(bits + (size_t)b * (Ln * TB));
    ulonglong2* s2 = (ulonglong2*)sb;
    #pragma unroll
    for (int i = 0; i < 64; ++i) s2[i * 64 + lane] = g[i * 64 + lane];
    __syncthreads();
    if (lane != 0) return;

    int tl = ilen[b], ml = olen[b];
    int2* eb = ext + b * Ln;
    int r = tl - 1, hi = ml - 1, p = ml - 2;
    if (p < 0) { eb[r] = make_int2(0, hi); return; }
    int c = p >> 6;
    uint64_t w0 = sb[r * TB + c];
    uint64_t w1 = sb[(r > 0 ? r - 1 : 0) * TB + c];
    uint64_t w2 = sb[(r > 1 ? r - 2 : 0) * TB + c];
    uint64_t w3 = sb[(r > 2 ? r - 3 : 0) * TB + c];
    int vd = 3;
    while (true) {
        int pb = p & 63;
        uint64_t mask = (pb == 63) ? ~0ull : ((1ull << (pb + 1)) - 1ull);
        uint64_t m = w0 & mask;
        if (m == 0) {
            p = (p & ~63) - 1;
            if (p < 0) { eb[r] = make_int2(0, hi); break; }
            c = p >> 6;
            w0 = sb[r * TB + c];
            w1 = sb[(r > 0 ? r - 1 : 0) * TB + c];
            w2 = sb[(r > 1 ? r - 2 : 0) * TB + c];
            w3 = sb[(r > 2 ? r - 3 : 0) * TB + c];
            vd = 3;
        } else {
            int q = 63 - __builtin_clzll(m);
            int tq = (p & ~63) + q;
            eb[r] = make_int2(tq + 1, hi);
            r -= 1;
            if (r < 0) break;                   // saturation: remaining columns zero
            hi = tq;
            p = tq - 1;
            if (p < 0) { eb[r] = make_int2(0, hi); break; }
            w0 = w1; w1 = w2; w2 = w3; vd -= 1;
            int nc = p >> 6;
            if (nc != c || vd == 0) {
                c = nc;
                w0 = sb[r * TB + c];
                w1 = sb[(r > 0 ? r - 1 : 0) * TB + c];
                w2 = sb[(r > 1 ? r - 2 : 0) * TB + c];
                w3 = sb[(r > 2 ? r - 3 : 0) * TB + c];
                vd = 3;
            }
        }
    }
}

// ---------------- aligned-float4 fill from extents + fused final loss reduce ----------------
__global__ void k_fill(const int2* __restrict__ ext, const float* __restrict__ partial,
                       const int* __restrict__ olen, float* __restrict__ out) {
    const int NG = (Bn * Ln * Tn) / 4;          // 4,194,304 aligned float4 groups
    int idx = blockIdx.x * blockDim.x + threadIdx.x;
    int stride = gridDim.x * blockDim.x;
    for (int i = idx; i < NG; i += stride) {
        if (i == 0) {
            int2 e = ext[0];                     // out[1..3] = align f=0..2 (row 0)
            out[1] = (0 >= e.x && 0 <= e.y) ? 1.f : 0.f;
            out[2] = (1 >= e.x && 1 <= e.y) ? 1.f : 0.f;
            out[3] = (2 >= e.x && 2 <= e.y) ? 1.f : 0.f;
            int2 el = ext[Bn * Ln - 1];          // last element: row 8191, t=2047
            out[(size_t)Bn * Ln * Tn] = (2047 >= el.x && 2047 <= el.y) ? 1.f : 0.f;
            continue;
        }
        int f0 = 4 * i - 1;                      // align flat index of out[4i]
        int r0 = f0 >> 11;
        int t0 = f0 & 2047;
        int2 e0 = ext[r0];
        float4 v;
        if (t0 != 2047) {                        // all 4 in row r0
            v.x = (t0     >= e0.x && t0     <= e0.y) ? 1.f : 0.f;
            v.y = (t0 + 1 >= e0.x && t0 + 1 <= e0.y) ? 1.f : 0.f;
            v.z = (t0 + 2 >= e0.x && t0 + 2 <= e0.y) ? 1.f : 0.f;
            v.w = (t0 + 3 >= e0.x && t0 + 3 <= e0.y) ? 1.f : 0.f;
        } else {                                 // crosses into row r0+1 (t=0,1,2)
            int2 e1 = ext[r0 + 1];
            v.x = (2047 >= e0.x && 2047 <= e0.y) ? 1.f : 0.f;
            v.y = (0 >= e1.x && 0 <= e1.y) ? 1.f : 0.f;
            v.z = (1 >= e1.x && 1 <= e1.y) ? 1.f : 0.f;
            v.w = (2 >= e1.x && 2 <= e1.y) ? 1.f : 0.f;
        }
        *reinterpret_cast<float4*>(out + (size_t)4 * i) = v;
    }
    if (blockIdx.x == 0) {                       // fused deterministic loss reduce
        int tid = threadIdx.x;
        float acc = 0.f;
        for (int i = tid; i < 1024; i += 256) acc += partial[i];
        for (int off = 32; off > 0; off >>= 1) acc += __shfl_down(acc, off, 64);
        __shared__ float sw[4];
        if ((tid & 63) == 0) sw[tid >> 6] = acc;
        __syncthreads();
        if (tid == 0) {
            float tot = (sw[0] + sw[1]) + (sw[2] + sw[3]);
            int so = 0;
            for (int i = 0; i < Bn; ++i) so += olen[i];
            out[0] = tot / (float)so;
        }
    }
}

extern "C" void kernel_launch(void* const* d_in, const int* in_sizes, int n_in,
                              void* d_out, int out_size, void* d_ws, size_t ws_size,
                              hipStream_t stream) {
    const float* logp = (const float*)d_in[0];
    const float* att  = (const float*)d_in[1];
    const int* tlen   = (const int*)d_in[2];
    const int* mlen   = (const int*)d_in[3];
    float* out = (float*)d_out;
    uint64_t* bits = (uint64_t*)d_ws;                                   // 2 MB
    float* partial = (float*)((char*)d_ws + (size_t)Bn * Ln * TB * 8);  // +4 KB
    int2* ext = (int2*)((char*)d_ws + (size_t)Bn * Ln * TB * 8 + 4096); // +64 KB

    // 1) transpose logp into d_out scratch + loss partials
    k_trans_loss<<<5120, 256, 0, stream>>>(logp, att, tlen, mlen, out, partial);
    // 2) forward DP: LDS-staged pipeline + DPP + 8-deep reg prefetch, bits -> ws
    k_forward5<<<Bn, 64, 0, stream>>>(logp, out, bits);
    // 3) backtrack -> per-row run extents
    k_backtrack3<<<Bn, 64, 0, stream>>>(bits, tlen, mlen, ext);
    // 4) write full 0/1 output from extents + final loss reduce (overwrites scratch)
    k_fill<<<2048, 256, 0, stream>>>(ext, partial, mlen, out);
}